// Round 12
// baseline (347.199 us; speedup 1.0000x reference)
//
#include <hip/hip_runtime.h>

#define N_NODES 50000
#define N_EDGES 1000000
#define EMB     64
#define HID     128
#define NLAYER  3
#define NGRAPH  250
#define XFD     7
#define EFD     5
#define BN_EPS  1e-5f

// two-level counting sort geometry
#define BKT_SH 8
#define BKT_SZ 256
#define NBKT   ((N_NODES + BKT_SZ - 1) / BKT_SZ)  // 196
#define CHKE   4096
#define NCHK   ((N_EDGES + CHKE - 1) / CHKE)      // 245
#define CNTM   (NBKT * NCHK)                      // 48020
#define NB2    ((CNTM + 255) / 256)               // 188

typedef short bf8_t __attribute__((ext_vector_type(8)));   // 8 bf16 (4 VGPRs)
typedef float f4_t  __attribute__((ext_vector_type(4)));   // MFMA acc

union FragU {
    uint4 q;
    bf8_t v;
    unsigned short u[8];
};

__device__ __forceinline__ void atomAddF(float* p, float v) {
    __hip_atomic_fetch_add(p, v, __ATOMIC_RELAXED, __HIP_MEMORY_SCOPE_AGENT);
}

__device__ __forceinline__ unsigned short f2bf(float f) {
    unsigned int u = __float_as_uint(f);
    u += 0x7fffu + ((u >> 16) & 1u);
    return (unsigned short)(u >> 16);
}
__device__ __forceinline__ float bf2f(unsigned short s) {
    return __uint_as_float(((unsigned int)s) << 16);
}
__device__ __forceinline__ float4 bf4(ushort4 u) {
    return make_float4(bf2f(u.x), bf2f(u.y), bf2f(u.z), bf2f(u.w));
}

// h(bf16) = x @ xW + xb
__global__ void k_input(const float* __restrict__ x, const float* __restrict__ xW,
                        const float* __restrict__ xb, unsigned short* __restrict__ h) {
    int gid = blockIdx.x * 256 + threadIdx.x;
    if (gid >= N_NODES * EMB) return;
    int n = gid >> 6, f = gid & 63;
    float acc = xb[f];
#pragma unroll
    for (int k = 0; k < XFD; ++k) acc = fmaf(x[n * XFD + k], xW[k * EMB + f], acc);
    h[gid] = f2bf(acc);
}

// Pack W1/W2 into MFMA B-fragment order (one-time)
__global__ void k_packW(const float* __restrict__ W1, const float* __restrict__ W2,
                        unsigned short* __restrict__ pw1, unsigned short* __restrict__ pw2) {
    int gid = blockIdx.x * 256 + threadIdx.x;
    int layer = gid >> 14;
    int r = gid & 16383;
    if (layer >= NLAYER) return;
    if (r < 8192) {
        int p = r;
        int j = p & 7, lane = (p >> 3) & 63, ts = p >> 9;
        int t = ts >> 1, s = ts & 1;
        int k = 32 * s + 8 * (lane >> 4) + j;
        int n = 16 * t + (lane & 15);
        pw1[layer * 8192 + p] = f2bf(W1[layer * EMB * HID + k * HID + n]);
    } else {
        int p = r - 8192;
        int j = p & 7, lane = (p >> 3) & 63, ts = p >> 9;
        int t = ts >> 2, s = ts & 3;
        int k = 32 * s + 8 * (lane >> 4) + j;
        int n = 16 * t + (lane & 15);
        pw2[layer * 8192 + p] = f2bf(W2[layer * HID * EMB + k * EMB + n]);
    }
}

// ---- phase A: per-chunk coarse-bucket histogram ----
__global__ __launch_bounds__(256) void k_binA(const int* __restrict__ dst,
                                              int* __restrict__ cntmat) {
    __shared__ int hist[NBKT];
    int tid = threadIdx.x, c = blockIdx.x;
    for (int i = tid; i < NBKT; i += 256) hist[i] = 0;
    __syncthreads();
    int e0 = c * CHKE, e1 = min(e0 + CHKE, N_EDGES);
    for (int i = e0 + tid; i < e1; i += 256) atomicAdd(&hist[dst[i] >> BKT_SH], 1);
    __syncthreads();
    for (int b = tid; b < NBKT; b += 256) cntmat[b * NCHK + c] = hist[b];
}

// ---- 3-phase multi-block exclusive scan ----
__global__ __launch_bounds__(256) void k_gscanA(const int* __restrict__ in, int n,
                                                int* __restrict__ bsum) {
    int tid = threadIdx.x, lane = tid & 63, wid = tid >> 6;
    int i = blockIdx.x * 256 + tid;
    int v = (i < n) ? in[i] : 0;
#pragma unroll
    for (int off = 32; off; off >>= 1) v += __shfl_down(v, off);
    __shared__ int ws[4];
    if (lane == 0) ws[wid] = v;
    __syncthreads();
    if (tid == 0) bsum[blockIdx.x] = ws[0] + ws[1] + ws[2] + ws[3];
}

__global__ __launch_bounds__(256) void k_gscanB(const int* __restrict__ bsum, int nb,
                                                int* __restrict__ boff) {
    int tid = threadIdx.x, lane = tid & 63, wid = tid >> 6;
    int v = (tid < nb) ? bsum[tid] : 0;
    int x = v;
#pragma unroll
    for (int off = 1; off < 64; off <<= 1) {
        int y = __shfl_up(x, off);
        if (lane >= off) x += y;
    }
    __shared__ int wtot[4];
    if (lane == 63) wtot[wid] = x;
    __syncthreads();
    int woff = 0;
    for (int w = 0; w < wid; ++w) woff += wtot[w];
    if (tid < nb) boff[tid] = woff + x - v;
}

__global__ __launch_bounds__(256) void k_gscanC(const int* __restrict__ in, int n,
                                                const int* __restrict__ boff,
                                                int* __restrict__ out) {
    int tid = threadIdx.x, lane = tid & 63, wid = tid >> 6;
    int i = blockIdx.x * 256 + tid;
    int v = (i < n) ? in[i] : 0;
    int x = v;
#pragma unroll
    for (int off = 1; off < 64; off <<= 1) {
        int y = __shfl_up(x, off);
        if (lane >= off) x += y;
    }
    __shared__ int wtot[4];
    if (lane == 63) wtot[wid] = x;
    __syncthreads();
    int woff = boff[blockIdx.x];
    for (int w = 0; w < wid; ++w) woff += wtot[w];
    if (i < n) out[i] = woff + x - v;
}

// ---- phase C: coarse scatter of packed {src, d_local<<20|eid} ----
__global__ __launch_bounds__(256) void k_binC(const int* __restrict__ src,
                                              const int* __restrict__ dst,
                                              const int* __restrict__ off2,
                                              int2* __restrict__ bufSD) {
    __shared__ int cur[NBKT];
    int tid = threadIdx.x, c = blockIdx.x;
    for (int b = tid; b < NBKT; b += 256) cur[b] = off2[b * NCHK + c];
    __syncthreads();
    int e0 = c * CHKE, e1 = min(e0 + CHKE, N_EDGES);
    for (int i = e0 + tid; i < e1; i += 256) {
        int d = dst[i];
        int b = d >> BKT_SH;
        int p = atomicAdd(&cur[b], 1);
        bufSD[p] = make_int2(src[i], ((d & (BKT_SZ - 1)) << 20) | i);
    }
}

// ---- phase D: per-bucket fine sort -> csr + csrE + rowstart ----
__global__ __launch_bounds__(256) void k_binD(const int2* __restrict__ bufSD,
                                              const int* __restrict__ off2,
                                              int* __restrict__ csr,
                                              int* __restrict__ csrE,
                                              int* __restrict__ rowstart) {
    __shared__ int hist[BKT_SZ];
    __shared__ int cur[BKT_SZ];
    __shared__ int wtot[4];
    int tid = threadIdx.x, b = blockIdx.x;
    int bstart = off2[b * NCHK];
    int bend = (b + 1 < NBKT) ? off2[(b + 1) * NCHK] : N_EDGES;
    hist[tid] = 0;
    __syncthreads();
    for (int j = bstart + tid; j < bend; j += 256)
        atomicAdd(&hist[bufSD[j].y >> 20], 1);
    __syncthreads();
    int lane = tid & 63, wid = tid >> 6;
    int v = hist[tid], x = v;
#pragma unroll
    for (int off = 1; off < 64; off <<= 1) {
        int y = __shfl_up(x, off);
        if (lane >= off) x += y;
    }
    if (lane == 63) wtot[wid] = x;
    __syncthreads();
    int woff = 0;
    for (int w = 0; w < wid; ++w) woff += wtot[w];
    int ex = woff + x - v;
    cur[tid] = ex;
    int node = b * BKT_SZ + tid;
    if (node < N_NODES) rowstart[node] = bstart + ex;
    if (b == NBKT - 1 && tid == 0) rowstart[N_NODES] = N_EDGES;
    __syncthreads();
    for (int j = bstart + tid; j < bend; j += 256) {
        int2 t = bufSD[j];
        int local = t.y >> 20;
        int p = atomicAdd(&cur[local], 1);
        csr[bstart + p] = t.x;
        csrE[bstart + p] = t.y & 0xFFFFF;
    }
}

// aggE[n] = sum of ea over in-edges (wave/node, full-device concurrency)
__global__ __launch_bounds__(256) void k_aggE(const int* __restrict__ rowstart,
                                              const int* __restrict__ csrE,
                                              const float* __restrict__ ea,
                                              float* __restrict__ aggE) {
    int wid = (blockIdx.x * 256 + threadIdx.x) >> 6;
    int lane = threadIdx.x & 63;
    if (wid >= N_NODES) return;
    int j0 = rowstart[wid], j1 = rowstart[wid + 1];
    float s0 = 0.f, s1 = 0.f, s2 = 0.f, s3 = 0.f, s4 = 0.f;
    for (int j = j0 + lane; j < j1; j += 64) {
        int e = csrE[j];
        const float* p = ea + (size_t)e * EFD;
        s0 += p[0]; s1 += p[1]; s2 += p[2]; s3 += p[3]; s4 += p[4];
    }
#pragma unroll
    for (int off = 32; off; off >>= 1) {
        s0 += __shfl_down(s0, off);
        s1 += __shfl_down(s1, off);
        s2 += __shfl_down(s2, off);
        s3 += __shfl_down(s3, off);
        s4 += __shfl_down(s4, off);
    }
    if (lane == 0) {
        float* o = aggE + (size_t)wid * EFD;
        o[0] = s0; o[1] = s1; o[2] = s2; o[3] = s3; o[4] = s4;
    }
}

#define ACC4(acc, u) { float4 _v = bf4(u); acc.x += _v.x; acc.y += _v.y; acc.z += _v.z; acc.w += _v.w; }

// agg(bf16 out): wave = 4 nodes as 2 pipelined pairs — both nodes' gathers in
// flight per waitcnt (8 loads/lane, 32 rows) to double memory-level parallelism
// (R11: k_agg at ~3.4TB/s, far under BW ceilings => latency/MLP-bound theory).
// Emits bf16 directly: k_mlp quantizes A to bf16 anyway — zero accuracy cost.
__global__ __launch_bounds__(256) void k_agg(const unsigned short* __restrict__ h,
                                             unsigned short* __restrict__ aggb,
                                             const int* __restrict__ rowstart,
                                             const int* __restrict__ csr,
                                             const float* __restrict__ aggE,
                                             const float* __restrict__ eWl,
                                             const float* __restrict__ ebl) {
    int wave = (blockIdx.x * 256 + threadIdx.x) >> 6;
    int lane = threadIdx.x & 63;
    int nbase = wave * 4;                 // N_NODES % 4 == 0
    if (nbase >= N_NODES) return;
    int lg = lane >> 4, lq = lane & 15;
    const ushort4* hb = (const ushort4*)h;
    const float4* eW4 = (const float4*)eWl;
    float4 ew0 = eW4[lq], ew1 = eW4[16 + lq], ew2 = eW4[32 + lq],
           ew3 = eW4[48 + lq], ew4 = eW4[64 + lq];
    float4 eb4 = ((const float4*)ebl)[lq];
#pragma unroll
    for (int half = 0; half < 2; ++half) {
        int nA = nbase + half * 2;
        int nB = nA + 1;
        int rA0 = rowstart[nA], rA1 = rowstart[nA + 1], rB1 = rowstart[nB + 1];
        int jA = rA0, jB = rA1;
        float4 accA = make_float4(0.f, 0.f, 0.f, 0.f);
        float4 accB = make_float4(0.f, 0.f, 0.f, 0.f);
        while (jA < rA1 || jB < rB1) {
            int takeA = min(rA1 - jA, 64); if (takeA < 0) takeA = 0;
            int takeB = min(rB1 - jB, 64); if (takeB < 0) takeB = 0;
            int myA = (lane < takeA) ? csr[jA + lane] : 0;
            int myB = (lane < takeB) ? csr[jB + lane] : 0;
            int nt = (max(takeA, takeB) + 3) >> 2;
            int t = 0;
            for (; t + 4 <= nt; t += 4) {
                int e0 = t * 4 + lg, e1 = e0 + 4, e2 = e0 + 8, e3 = e0 + 12;
                int sA0 = __shfl(myA, e0), sA1 = __shfl(myA, e1),
                    sA2 = __shfl(myA, e2), sA3 = __shfl(myA, e3);
                int sB0 = __shfl(myB, e0), sB1 = __shfl(myB, e1),
                    sB2 = __shfl(myB, e2), sB3 = __shfl(myB, e3);
                ushort4 uA0 = hb[(size_t)sA0 * 16 + lq];
                ushort4 uA1 = hb[(size_t)sA1 * 16 + lq];
                ushort4 uA2 = hb[(size_t)sA2 * 16 + lq];
                ushort4 uA3 = hb[(size_t)sA3 * 16 + lq];
                ushort4 uB0 = hb[(size_t)sB0 * 16 + lq];
                ushort4 uB1 = hb[(size_t)sB1 * 16 + lq];
                ushort4 uB2 = hb[(size_t)sB2 * 16 + lq];
                ushort4 uB3 = hb[(size_t)sB3 * 16 + lq];
                if (e0 < takeA) ACC4(accA, uA0);
                if (e1 < takeA) ACC4(accA, uA1);
                if (e2 < takeA) ACC4(accA, uA2);
                if (e3 < takeA) ACC4(accA, uA3);
                if (e0 < takeB) ACC4(accB, uB0);
                if (e1 < takeB) ACC4(accB, uB1);
                if (e2 < takeB) ACC4(accB, uB2);
                if (e3 < takeB) ACC4(accB, uB3);
            }
            for (; t < nt; ++t) {
                int e = t * 4 + lg;
                int sA = __shfl(myA, e), sB = __shfl(myB, e);
                ushort4 uA = hb[(size_t)sA * 16 + lq];
                ushort4 uB = hb[(size_t)sB * 16 + lq];
                if (e < takeA) ACC4(accA, uA);
                if (e < takeB) ACC4(accB, uB);
            }
            jA += takeA;
            jB += takeB;
        }
        // cross-group reductions for both nodes
        accA.x += __shfl_xor(accA.x, 16); accA.y += __shfl_xor(accA.y, 16);
        accA.z += __shfl_xor(accA.z, 16); accA.w += __shfl_xor(accA.w, 16);
        accA.x += __shfl_xor(accA.x, 32); accA.y += __shfl_xor(accA.y, 32);
        accA.z += __shfl_xor(accA.z, 32); accA.w += __shfl_xor(accA.w, 32);
        accB.x += __shfl_xor(accB.x, 16); accB.y += __shfl_xor(accB.y, 16);
        accB.z += __shfl_xor(accB.z, 16); accB.w += __shfl_xor(accB.w, 16);
        accB.x += __shfl_xor(accB.x, 32); accB.y += __shfl_xor(accB.y, 32);
        accB.x += 0.f;
        accB.z += __shfl_xor(accB.z, 32); accB.w += __shfl_xor(accB.w, 32);
#pragma unroll
        for (int pick = 0; pick < 2; ++pick) {
            int n = pick ? nB : nA;
            float4 acc = pick ? accB : accA;
            int deg = (pick ? (rB1 - rA1) : (rA1 - rA0));
            float a0 = aggE[n * 5 + 0], a1 = aggE[n * 5 + 1], a2 = aggE[n * 5 + 2],
                  a3 = aggE[n * 5 + 3], a4 = aggE[n * 5 + 4];
            float c0 = a0 + 8.f;
            float ce = (float)deg + 1.f;
            float4 bb = bf4(hb[(size_t)n * 16 + lq]);
            bb.x = fmaf(c0, ew0.x, bb.x); bb.y = fmaf(c0, ew0.y, bb.y);
            bb.z = fmaf(c0, ew0.z, bb.z); bb.w = fmaf(c0, ew0.w, bb.w);
            bb.x = fmaf(a1, ew1.x, bb.x); bb.y = fmaf(a1, ew1.y, bb.y);
            bb.z = fmaf(a1, ew1.z, bb.z); bb.w = fmaf(a1, ew1.w, bb.w);
            bb.x = fmaf(a2, ew2.x, bb.x); bb.y = fmaf(a2, ew2.y, bb.y);
            bb.z = fmaf(a2, ew2.z, bb.z); bb.w = fmaf(a2, ew2.w, bb.w);
            bb.x = fmaf(a3, ew3.x, bb.x); bb.y = fmaf(a3, ew3.y, bb.y);
            bb.z = fmaf(a3, ew3.z, bb.z); bb.w = fmaf(a3, ew3.w, bb.w);
            bb.x = fmaf(a4, ew4.x, bb.x); bb.y = fmaf(a4, ew4.y, bb.y);
            bb.z = fmaf(a4, ew4.z, bb.z); bb.w = fmaf(a4, ew4.w, bb.w);
            bb.x = fmaf(ce, eb4.x, bb.x); bb.y = fmaf(ce, eb4.y, bb.y);
            bb.z = fmaf(ce, eb4.z, bb.z); bb.w = fmaf(ce, eb4.w, bb.w);
            if (lg == 0) {
                ushort4 o;
                o.x = f2bf(acc.x + bb.x);
                o.y = f2bf(acc.y + bb.y);
                o.z = f2bf(acc.z + bb.z);
                o.w = f2bf(acc.w + bb.w);
                ((ushort4*)aggb)[(size_t)n * 16 + lq] = o;
            }
        }
    }
}

// Fused MLP via MFMA. A (agg) now bf16 in memory -> direct uint4 frag loads.
__global__ __launch_bounds__(256) void k_mlp(const unsigned short* __restrict__ aggb,
                                             float* __restrict__ h2,
                                             const unsigned short* __restrict__ pw1,
                                             const float* __restrict__ b1l,
                                             const unsigned short* __restrict__ pw2,
                                             const float* __restrict__ b2l,
                                             float* __restrict__ stats) {
    __shared__ __align__(16) unsigned short hid[64 * 136];  // [m][j], 17.4KB
    int tid = threadIdx.x;
    int w = tid >> 6, lane = tid & 63;
    int q = lane >> 4, l15 = lane & 15;
    int n0 = blockIdx.x * 64;
    // ---- phase 1: hidden = relu(agg @ W1 + b1) ----
    int mrow = n0 + 16 * w + l15;
    const unsigned short* arow =
        aggb + (size_t)(mrow < N_NODES ? mrow : N_NODES - 1) * EMB;
    FragU fa[2];
    fa[0].q = *(const uint4*)&arow[8 * q];
    fa[1].q = *(const uint4*)&arow[32 + 8 * q];
    const uint4* w1f = (const uint4*)pw1;
    f4_t acc1[8];
#pragma unroll
    for (int t = 0; t < 8; ++t) {
        acc1[t] = (f4_t){0.f, 0.f, 0.f, 0.f};
        FragU b0, b1;
        b0.q = w1f[(t * 2 + 0) * 64 + lane];
        b1.q = w1f[(t * 2 + 1) * 64 + lane];
        acc1[t] = __builtin_amdgcn_mfma_f32_16x16x32_bf16(fa[0].v, b0.v, acc1[t], 0, 0, 0);
        acc1[t] = __builtin_amdgcn_mfma_f32_16x16x32_bf16(fa[1].v, b1.v, acc1[t], 0, 0, 0);
    }
#pragma unroll
    for (int t = 0; t < 8; ++t) {
        int col = 16 * t + l15;
        float bv = b1l[col];
#pragma unroll
        for (int r = 0; r < 4; ++r) {
            int m = 16 * w + q * 4 + r;
            hid[m * 136 + col] = f2bf(fmaxf(acc1[t][r] + bv, 0.f));
        }
    }
    // ---- phase 2: h2 = hidden @ W2 + b2 (wave-local hid) ----
    FragU fa2[4];
#pragma unroll
    for (int s = 0; s < 4; ++s)
        fa2[s].q = *(const uint4*)&hid[(16 * w + l15) * 136 + 32 * s + 8 * q];
    const uint4* w2f = (const uint4*)pw2;
    f4_t acc2[4];
#pragma unroll
    for (int t = 0; t < 4; ++t) {
        acc2[t] = (f4_t){0.f, 0.f, 0.f, 0.f};
#pragma unroll
        for (int s = 0; s < 4; ++s) {
            FragU b;
            b.q = w2f[(t * 4 + s) * 64 + lane];
            acc2[t] = __builtin_amdgcn_mfma_f32_16x16x32_bf16(fa2[s].v, b.v, acc2[t], 0, 0, 0);
        }
    }
    float sacc[4] = {0.f, 0.f, 0.f, 0.f}, qacc[4] = {0.f, 0.f, 0.f, 0.f};
#pragma unroll
    for (int t = 0; t < 4; ++t) {
        int col = 16 * t + l15;
        float bv = b2l[col];
#pragma unroll
        for (int r = 0; r < 4; ++r) {
            int nn = n0 + 16 * w + q * 4 + r;
            if (nn < N_NODES) {
                float v = acc2[t][r] + bv;
                h2[(size_t)nn * EMB + col] = v;
                sacc[t] += v;
                qacc[t] = fmaf(v, v, qacc[t]);
            }
        }
    }
#pragma unroll
    for (int t = 0; t < 4; ++t) {
        sacc[t] += __shfl_xor(sacc[t], 16); qacc[t] += __shfl_xor(qacc[t], 16);
        sacc[t] += __shfl_xor(sacc[t], 32); qacc[t] += __shfl_xor(qacc[t], 32);
    }
    __syncthreads();
    float* red = (float*)hid;
    if (q == 0) {
#pragma unroll
        for (int t = 0; t < 4; ++t) {
            red[w * 64 + 16 * t + l15] = sacc[t];
            red[256 + w * 64 + 16 * t + l15] = qacc[t];
        }
    }
    __syncthreads();
    if (tid < 64) {
        float s = red[tid] + red[64 + tid] + red[128 + tid] + red[192 + tid];
        float qq = red[256 + tid] + red[320 + tid] + red[384 + tid] + red[448 + tid];
        atomAddF(&stats[tid], s);
        atomAddF(&stats[64 + tid], qq);
    }
}

// BN apply + ELU (layers 0,1): h(bf16) = elu(bn(h2))
__global__ void k_bn(const float* __restrict__ h2, unsigned short* __restrict__ h,
                     const float* __restrict__ stats, const float* __restrict__ gam,
                     const float* __restrict__ bet) {
    int gid = blockIdx.x * 256 + threadIdx.x;
    if (gid >= N_NODES * EMB) return;
    int f = gid & 63;
    const float invN = 1.f / (float)N_NODES;
    float mean = stats[f] * invN;
    float var = stats[64 + f] * invN - mean * mean;
    float inv = rsqrtf(var + BN_EPS);
    float v = (h2[gid] - mean) * inv * gam[f] + bet[f];
    h[gid] = f2bf(v > 0.f ? v : expm1f(v));
}

// last layer: BN only for the 250 super-nodes (h2 stays fp32)
__global__ void k_bnout(const float* __restrict__ h2, const int* __restrict__ last,
                        const float* __restrict__ stats, const float* __restrict__ gam,
                        const float* __restrict__ bet, float* __restrict__ out) {
    int gid = blockIdx.x * 256 + threadIdx.x;
    if (gid >= NGRAPH * EMB) return;
    int b = gid >> 6, f = gid & 63;
    const float invN = 1.f / (float)N_NODES;
    float mean = stats[f] * invN;
    float var = stats[64 + f] * invN - mean * mean;
    float inv = rsqrtf(var + BN_EPS);
    out[gid] = (h2[last[b] * EMB + f] - mean) * inv * gam[f] + bet[f];
}

extern "C" void kernel_launch(void* const* d_in, const int* in_sizes, int n_in,
                              void* d_out, int out_size, void* d_ws, size_t ws_size,
                              hipStream_t stream) {
    const float* x   = (const float*)d_in[0];
    const float* ea  = (const float*)d_in[1];
    const int*   eidx= (const int*)d_in[2];
    const int*   last= (const int*)d_in[3];
    const float* xW  = (const float*)d_in[4];
    const float* xb  = (const float*)d_in[5];
    const float* eW  = (const float*)d_in[6];
    const float* eb  = (const float*)d_in[7];
    const float* W1  = (const float*)d_in[8];
    const float* b1  = (const float*)d_in[9];
    const float* W2  = (const float*)d_in[10];
    const float* b2  = (const float*)d_in[11];
    const float* gam = (const float*)d_in[12];
    const float* bet = (const float*)d_in[13];
    float* out = (float*)d_out;

    const int* srcI = eidx;
    const int* dstI = eidx + N_EDGES;

    float* hslot  = (float*)d_ws;              // h bf16 uses half this slot
    float* agg    = hslot + N_NODES * EMB;     // h2 f32 in loop
    float* hidslot= agg + N_NODES * EMB;       // csrE alias pre-loop; aggb in loop
    float* aggE   = hidslot + N_NODES * HID;
    float* stats  = aggE + NBKT * BKT_SZ * EFD;
    int* rowstart = (int*)(stats + NLAYER * 2 * EMB);
    int* csr      = rowstart + N_NODES + 1;
    int* cntmat   = csr + N_EDGES;
    int* off2     = cntmat + CNTM;
    int* bsum     = off2 + CNTM;
    int* boff     = bsum + NB2;
    unsigned short* pw1 = (unsigned short*)(boff + NB2);   // 3*8192 bf16
    unsigned short* pw2 = pw1 + NLAYER * EMB * HID;        // 3*8192 bf16
    unsigned short* h = (unsigned short*)hslot;
    unsigned short* aggb = (unsigned short*)hidslot;       // bf16 agg (6.4MB)
    int2* bufSD   = (int2*)agg;                // alias, dead before loop
    int*  csrE    = (int*)hidslot;             // alias, dead after aggE

    hipMemsetAsync(stats, 0, NLAYER * 2 * EMB * sizeof(float), stream);

    k_input<<<(N_NODES * EMB + 255) / 256, 256, 0, stream>>>(x, xW, xb, h);
    k_packW<<<(NLAYER * 2 * EMB * HID + 255) / 256, 256, 0, stream>>>(W1, W2, pw1, pw2);
    k_binA<<<NCHK, 256, 0, stream>>>(dstI, cntmat);
    k_gscanA<<<NB2, 256, 0, stream>>>(cntmat, CNTM, bsum);
    k_gscanB<<<1, 256, 0, stream>>>(bsum, NB2, boff);
    k_gscanC<<<NB2, 256, 0, stream>>>(cntmat, CNTM, boff, off2);
    k_binC<<<NCHK, 256, 0, stream>>>(srcI, dstI, off2, bufSD);
    k_binD<<<NBKT, 256, 0, stream>>>(bufSD, off2, csr, csrE, rowstart);
    k_aggE<<<(N_NODES * 64 + 255) / 256, 256, 0, stream>>>(rowstart, csrE, ea, aggE);

    const int aggBlocks = ((N_NODES + 3) / 4 * 64 + 255) / 256;  // 4 nodes/wave
    const int mlpBlocks = (N_NODES + 63) / 64;
    for (int l = 0; l < NLAYER; ++l) {
        k_agg<<<aggBlocks, 256, 0, stream>>>(
            h, aggb, rowstart, csr, aggE, eW + l * EFD * EMB, eb + l * EMB);
        k_mlp<<<mlpBlocks, 256, 0, stream>>>(aggb, agg, pw1 + l * EMB * HID, b1 + l * HID,
                                             pw2 + l * HID * EMB, b2 + l * EMB,
                                             stats + l * 2 * EMB);
        if (l < NLAYER - 1) {
            k_bn<<<(N_NODES * EMB + 255) / 256, 256, 0, stream>>>(
                agg, h, stats + l * 2 * EMB, gam + l * EMB, bet + l * EMB);
        } else {
            k_bnout<<<(NGRAPH * EMB + 255) / 256, 256, 0, stream>>>(
                agg, last, stats + l * 2 * EMB, gam + l * EMB, bet + l * EMB, out);
        }
    }
}